// Round 6
// baseline (505.347 us; speedup 1.0000x reference)
//
#include <hip/hip_runtime.h>
#include <hip/hip_fp16.h>

#define N_NODES 100000
#define N_EDGES 1280000
#define N_GRAPHS 512
#define SCAN_BLOCKS 391      // ceil(100000/256)
#define N_BUCKETS 782        // ceil(100000/128), bucket = dst >> 7
#define BUCKET_CAP 2560      // mean 1638, sigma ~40; 22 sigma of headroom

// ---------------- degree count ----------------

__global__ void count_deg(const int* __restrict__ dst, int* __restrict__ cnt) {
    int e = blockIdx.x * blockDim.x + threadIdx.x;
    if (e < N_EDGES) atomicAdd(&cnt[dst[e]], 1);
}

// ---------------- exclusive prefix scan (3-kernel), scan1 also emits dinv ----

__global__ void scan1(const int* __restrict__ cnt, int* __restrict__ offs,
                      int* __restrict__ bsum, float* __restrict__ dinv) {
    __shared__ int s[256];
    int t = threadIdx.x;
    int i = blockIdx.x * 256 + t;
    int v = (i < N_NODES) ? cnt[i] : 0;
    if (i < N_NODES) dinv[i] = 1.0f / sqrtf((float)v + 1.0f);
    s[t] = v; __syncthreads();
    for (int d = 1; d < 256; d <<= 1) {
        int x = (t >= d) ? s[t - d] : 0;
        __syncthreads();
        s[t] += x;
        __syncthreads();
    }
    if (i < N_NODES) offs[i] = s[t] - v;
    if (t == 255) bsum[blockIdx.x] = s[t];
}

__global__ void scan2(int* __restrict__ bsum, int nb) {
    __shared__ int s[512];
    int t = threadIdx.x;
    int v = (t < nb) ? bsum[t] : 0;
    s[t] = v; __syncthreads();
    for (int d = 1; d < 512; d <<= 1) {
        int x = (t >= d) ? s[t - d] : 0;
        __syncthreads();
        s[t] += x;
        __syncthreads();
    }
    if (t < nb) bsum[t] = s[t] - v;
}

__global__ void scan3(int* __restrict__ offs, const int* __restrict__ bsum) {
    int i = blockIdx.x * 256 + threadIdx.x;
    if (i < N_NODES) offs[i] += bsum[blockIdx.x];
    if (i == 0) offs[N_NODES] = N_EDGES;
}

// ---------------- bucketed CSR build ----------------
// Phase 0: init per-bucket cursors (padded to 64B to avoid same-line atomics).

__global__ void init_bcur(const int* __restrict__ offs, int* __restrict__ bcur) {
    int b = blockIdx.x * blockDim.x + threadIdx.x;
    if (b < N_BUCKETS) bcur[b * 16] = offs[b << 7];
}

// Phase 1: scatter (src,dst) pairs into bucket-grouped regions.
// 782 concurrent write streams -> L2 merges lines, no write amplification.

__global__ void bucket_scatter(const int* __restrict__ src, const int* __restrict__ dst,
                               int* __restrict__ bcur, int2* __restrict__ pairs) {
    int e = blockIdx.x * blockDim.x + threadIdx.x;
    if (e < N_EDGES) {
        int d = dst[e];
        int p = atomicAdd(&bcur[(d >> 7) * 16], 1);
        pairs[p] = make_int2(src[e], d);
    }
}

// Phase 2: one block per bucket; exact placement via LDS staging, stream out.

__global__ __launch_bounds__(256) void bucket_place(const int2* __restrict__ pairs,
                                                    const int* __restrict__ offs,
                                                    const float* __restrict__ dinv,
                                                    int2* __restrict__ rec) {
    __shared__ int  lcur[128];
    __shared__ int2 lrec[BUCKET_CAP];   // 20 KB
    int b = blockIdx.x;
    int node0 = b << 7;
    int beg = offs[node0];
    int end = offs[min(node0 + 128, N_NODES)];
    int cnt = end - beg;
    if (threadIdx.x < 128) lcur[threadIdx.x] = 0;
    __syncthreads();
    for (int i = beg + threadIdx.x; i < end; i += 256) {
        int2 pr = pairs[i];
        int s = pr.x, d = pr.y;
        int idx = offs[d] - beg + atomicAdd(&lcur[d & 127], 1);
        int2 r = make_int2(s, __float_as_int(dinv[s] * dinv[d]));
        if (idx < BUCKET_CAP) lrec[idx] = r;
        else                  rec[beg + idx] = r;   // overflow fallback (never in practice)
    }
    __syncthreads();
    int lim = min(cnt, BUCKET_CAP);
    for (int j = threadIdx.x; j < lim; j += 256) rec[beg + j] = lrec[j];
}

// ---------------- fp32 GEMM [N x 64] @ [64 x 64], fp16 output ----------------
// R1-proven structure: acc[4][4] (16 VGPRs), no spills. DO NOT grow the
// accumulator tile: R2's acc[8][4] variant hit VGPR=256 -> scratch spills.

__global__ __launch_bounds__(256) void gemm64(const float* __restrict__ X,
                                              const float* __restrict__ W,
                                              __half* __restrict__ H) {
    __shared__ float Xt[64][68];   // transposed tile: Xt[k][node]
    __shared__ float Ws[64][64];   // Ws[k][j]
    int t = threadIdx.x;
    int base = blockIdx.x * 64;

    {
        const float4* Wv = (const float4*)W;
        float4* Wsv = (float4*)Ws;
        Wsv[t]        = Wv[t];
        Wsv[t + 256]  = Wv[t + 256];
        Wsv[t + 512]  = Wv[t + 512];
        Wsv[t + 768]  = Wv[t + 768];
    }
    {
        int r = t >> 2;
        int k0 = (t & 3) * 16;
        int row = base + r;
        if (row < N_NODES) {
            const float4* xr = (const float4*)(X + (size_t)row * 64 + k0);
            #pragma unroll
            for (int q = 0; q < 4; q++) {
                float4 v = xr[q];
                int k = k0 + q * 4;
                Xt[k + 0][r] = v.x; Xt[k + 1][r] = v.y;
                Xt[k + 2][r] = v.z; Xt[k + 3][r] = v.w;
            }
        } else {
            #pragma unroll
            for (int q = 0; q < 4; q++) {
                int k = k0 + q * 4;
                Xt[k][r] = 0.f; Xt[k + 1][r] = 0.f; Xt[k + 2][r] = 0.f; Xt[k + 3][r] = 0.f;
            }
        }
    }
    __syncthreads();

    int tx = t & 15, ty = t >> 4;
    int j0 = tx * 4, n0 = ty * 4;
    float acc[4][4] = {};
    #pragma unroll
    for (int k = 0; k < 64; k++) {
        float4 a = *(const float4*)&Xt[k][n0];
        float4 w = *(const float4*)&Ws[k][j0];
        acc[0][0] += a.x * w.x; acc[0][1] += a.x * w.y; acc[0][2] += a.x * w.z; acc[0][3] += a.x * w.w;
        acc[1][0] += a.y * w.x; acc[1][1] += a.y * w.y; acc[1][2] += a.y * w.z; acc[1][3] += a.y * w.w;
        acc[2][0] += a.z * w.x; acc[2][1] += a.z * w.y; acc[2][2] += a.z * w.z; acc[2][3] += a.z * w.w;
        acc[3][0] += a.w * w.x; acc[3][1] += a.w * w.y; acc[3][2] += a.w * w.z; acc[3][3] += a.w * w.w;
    }
    #pragma unroll
    for (int i = 0; i < 4; i++) {
        int row = base + n0 + i;
        if (row < N_NODES) {
            __half2 h01 = __float22half2_rn(make_float2(acc[i][0], acc[i][1]));
            __half2 h23 = __float22half2_rn(make_float2(acc[i][2], acc[i][3]));
            uint2 u;
            u.x = *(unsigned int*)&h01;
            u.y = *(unsigned int*)&h23;
            *(uint2*)((char*)H + (size_t)row * 128 + j0 * 2) = u;
        }
    }
}

// ------------- aggregation: wave per node, 4 edge-subgroups x 16 feature-quads -------------
// H is fp16 (row = 128B = 16 uint2 chunks); edge record = int2(src, norm).

__device__ inline void agg_body(const uint2* __restrict__ Hh, int wid, int lane,
                                const int* __restrict__ offs,
                                const int2* __restrict__ rec,
                                const float* __restrict__ dinv,
                                float4& out) {
    int eg = lane >> 4;       // 0..3
    int fq = lane & 15;       // feature quad
    int beg = offs[wid], end = offs[wid + 1];
    float di = dinv[wid];
    uint2 us = Hh[(size_t)wid * 16 + fq];

    float4 a0 = {0.f, 0.f, 0.f, 0.f};
    float4 a1 = {0.f, 0.f, 0.f, 0.f};
    int e = beg + eg;
    for (; e + 4 < end; e += 8) {
        int2 r0 = rec[e];
        int2 r1 = rec[e + 4];
        uint2 u0 = Hh[(size_t)r0.x * 16 + fq];
        uint2 u1 = Hh[(size_t)r1.x * 16 + fq];
        float n0 = __int_as_float(r0.y), n1 = __int_as_float(r1.y);
        float2 f00 = __half22float2(*(__half2*)&u0.x);
        float2 f01 = __half22float2(*(__half2*)&u0.y);
        float2 f10 = __half22float2(*(__half2*)&u1.x);
        float2 f11 = __half22float2(*(__half2*)&u1.y);
        a0.x += f00.x * n0; a0.y += f00.y * n0; a0.z += f01.x * n0; a0.w += f01.y * n0;
        a1.x += f10.x * n1; a1.y += f10.y * n1; a1.z += f11.x * n1; a1.w += f11.y * n1;
    }
    if (e < end) {
        int2 r0 = rec[e];
        uint2 u0 = Hh[(size_t)r0.x * 16 + fq];
        float n0 = __int_as_float(r0.y);
        float2 f00 = __half22float2(*(__half2*)&u0.x);
        float2 f01 = __half22float2(*(__half2*)&u0.y);
        a0.x += f00.x * n0; a0.y += f00.y * n0; a0.z += f01.x * n0; a0.w += f01.y * n0;
    }
    a0.x += a1.x; a0.y += a1.y; a0.z += a1.z; a0.w += a1.w;
    a0.x += __shfl_xor(a0.x, 16); a0.y += __shfl_xor(a0.y, 16);
    a0.z += __shfl_xor(a0.z, 16); a0.w += __shfl_xor(a0.w, 16);
    a0.x += __shfl_xor(a0.x, 32); a0.y += __shfl_xor(a0.y, 32);
    a0.z += __shfl_xor(a0.z, 32); a0.w += __shfl_xor(a0.w, 32);
    float2 s01 = __half22float2(*(__half2*)&us.x);
    float2 s23 = __half22float2(*(__half2*)&us.y);
    float dd = di * di;
    out.x = a0.x + s01.x * dd; out.y = a0.y + s01.y * dd;
    out.z = a0.z + s23.x * dd; out.w = a0.w + s23.y * dd;
}

__global__ __launch_bounds__(256) void agg_gcn(const __half* __restrict__ H,
                                               const int* __restrict__ offs,
                                               const int2* __restrict__ rec,
                                               const float* __restrict__ dinv,
                                               const float* __restrict__ bias,
                                               float* __restrict__ Out) {
    int wid = (blockIdx.x * 256 + threadIdx.x) >> 6;
    int lane = threadIdx.x & 63;
    if (wid >= N_NODES) return;
    float4 r;
    agg_body((const uint2*)H, wid, lane, offs, rec, dinv, r);
    int fq = lane & 15;
    if ((lane >> 4) == 0) {
        float4 b4 = ((const float4*)bias)[fq];
        float4 o;
        o.x = fmaxf(r.x + b4.x, 0.f); o.y = fmaxf(r.y + b4.y, 0.f);
        o.z = fmaxf(r.z + b4.z, 0.f); o.w = fmaxf(r.w + b4.w, 0.f);
        ((float4*)Out)[(size_t)wid * 16 + fq] = o;
    }
}

__global__ __launch_bounds__(256) void agg_gcn_pool(const __half* __restrict__ H,
                                                    const int* __restrict__ offs,
                                                    const int2* __restrict__ rec,
                                                    const float* __restrict__ dinv,
                                                    const float* __restrict__ bias,
                                                    const float* __restrict__ fcw,
                                                    float* __restrict__ p) {
    int wid = (blockIdx.x * 256 + threadIdx.x) >> 6;
    int lane = threadIdx.x & 63;
    if (wid >= N_NODES) return;
    float4 r;
    agg_body((const uint2*)H, wid, lane, offs, rec, dinv, r);
    int fq = lane & 15;
    float4 b4 = ((const float4*)bias)[fq];
    float4 f4 = ((const float4*)fcw)[fq];
    float v = fmaxf(r.x + b4.x, 0.f) * f4.x + fmaxf(r.y + b4.y, 0.f) * f4.y
            + fmaxf(r.z + b4.z, 0.f) * f4.z + fmaxf(r.w + b4.w, 0.f) * f4.w;
    v += __shfl_xor(v, 1); v += __shfl_xor(v, 2);
    v += __shfl_xor(v, 4); v += __shfl_xor(v, 8);
    if (lane == 0) p[wid] = v;
}

// ---------------- per-graph segmented mean via binary search (no atomics) ----

__device__ inline int lower_bound_batch(const int* __restrict__ batch, int key) {
    int lo = 0, hi = N_NODES;
    while (lo < hi) {
        int mid = (lo + hi) >> 1;
        if (batch[mid] < key) lo = mid + 1; else hi = mid;
    }
    return lo;
}

__global__ __launch_bounds__(256) void graph_reduce(const float* __restrict__ p,
                                                    const int* __restrict__ batch,
                                                    const float* __restrict__ fcb,
                                                    float* __restrict__ out) {
    __shared__ float red[4];
    int g = blockIdx.x;
    int s0 = lower_bound_batch(batch, g);
    int s1 = lower_bound_batch(batch, g + 1);
    float acc = 0.f;
    for (int i = s0 + threadIdx.x; i < s1; i += 256) acc += p[i];
    #pragma unroll
    for (int o = 32; o > 0; o >>= 1) acc += __shfl_xor(acc, o);
    int lane = threadIdx.x & 63, wv = threadIdx.x >> 6;
    if (lane == 0) red[wv] = acc;
    __syncthreads();
    if (threadIdx.x == 0) {
        float sum = red[0] + red[1] + red[2] + red[3];
        out[g] = sum / fmaxf((float)(s1 - s0), 1.f) + fcb[0];
    }
}

// ---------------- launch ----------------

extern "C" void kernel_launch(void* const* d_in, const int* in_sizes, int n_in,
                              void* d_out, int out_size, void* d_ws, size_t ws_size,
                              hipStream_t stream) {
    const float* x    = (const float*)d_in[0];
    const int*   ei   = (const int*)d_in[1];
    const int*   batch= (const int*)d_in[2];
    const float* w0   = (const float*)d_in[3];
    const float* b0   = (const float*)d_in[4];
    const float* w1   = (const float*)d_in[5];
    const float* b1   = (const float*)d_in[6];
    const float* w2   = (const float*)d_in[7];
    const float* b2   = (const float*)d_in[8];
    const float* fcw  = (const float*)d_in[9];
    const float* fcb  = (const float*)d_in[10];
    float* out = (float*)d_out;

    const int* src_e = ei;              // edge_index[0]
    const int* dst_e = ei + N_EDGES;    // edge_index[1]

    char* w = (char*)d_ws;
    size_t o = 0;
    int*    deg_cnt = (int*)(w + o);    o += (size_t)N_NODES * 4;
    float*  dinv    = (float*)(w + o);  o += (size_t)N_NODES * 4;
    int*    offs    = (int*)(w + o);    o += (size_t)(N_NODES + 8) * 4;  // N_NODES+1 used
    int*    bcur    = (int*)(w + o);    o += (size_t)N_BUCKETS * 16 * 4; // padded cursors
    int*    bsum    = (int*)(w + o);    o += 512 * 4;
    int2*   pairs   = (int2*)(w + o);   o += (size_t)N_EDGES * 8;        // 10.24MB
    int2*   rec     = (int2*)(w + o);   o += (size_t)N_EDGES * 8;        // 10.24MB
    __half* bufA    = (__half*)(w + o); o += (size_t)N_NODES * 64 * 2;   // 12.8MB fp16
    float*  bufB    = (float*)(w + o);  o += (size_t)N_NODES * 64 * 4;   // 25.6MB fp32
    float*  pvec    = (float*)(w + o);  o += (size_t)N_NODES * 4;

    hipMemsetAsync(deg_cnt, 0, (size_t)N_NODES * 4, stream);

    count_deg<<<(N_EDGES + 255) / 256, 256, 0, stream>>>(dst_e, deg_cnt);
    scan1<<<SCAN_BLOCKS, 256, 0, stream>>>(deg_cnt, offs, bsum, dinv);
    scan2<<<1, 512, 0, stream>>>(bsum, SCAN_BLOCKS);
    scan3<<<SCAN_BLOCKS, 256, 0, stream>>>(offs, bsum);
    init_bcur<<<(N_BUCKETS + 255) / 256, 256, 0, stream>>>(offs, bcur);
    bucket_scatter<<<(N_EDGES + 255) / 256, 256, 0, stream>>>(src_e, dst_e, bcur, pairs);
    bucket_place<<<N_BUCKETS, 256, 0, stream>>>(pairs, offs, dinv, rec);

    const int GEMM_BLOCKS = (N_NODES + 63) / 64;   // 1563
    const int AGG_BLOCKS  = (N_NODES + 3) / 4;     // 25000

    gemm64<<<GEMM_BLOCKS, 256, 0, stream>>>(x, w0, bufA);
    agg_gcn<<<AGG_BLOCKS, 256, 0, stream>>>(bufA, offs, rec, dinv, b0, bufB);

    gemm64<<<GEMM_BLOCKS, 256, 0, stream>>>(bufB, w1, bufA);
    agg_gcn<<<AGG_BLOCKS, 256, 0, stream>>>(bufA, offs, rec, dinv, b1, bufB);

    gemm64<<<GEMM_BLOCKS, 256, 0, stream>>>(bufB, w2, bufA);
    agg_gcn_pool<<<AGG_BLOCKS, 256, 0, stream>>>(bufA, offs, rec, dinv, b2, fcw, pvec);

    graph_reduce<<<N_GRAPHS, 256, 0, stream>>>(pvec, batch, fcb, out);
}

// Round 7
// 407.012 us; speedup vs baseline: 1.2416x; 1.2416x over previous
//
#include <hip/hip_runtime.h>
#include <hip/hip_fp16.h>

#define N_NODES 100000
#define N_EDGES 1280000
#define N_GRAPHS 512
#define NBK 196          // buckets of 512 dst nodes: ceil(100000/512)
#define CHUNK 6400       // edges per scatter block; 200*6400 == N_EDGES exactly
#define NCH 200
#define PLACE_CAP 8192   // bucket mean 6554, sigma ~80 -> 20 sigma headroom

// ---------------- pass 1: per-chunk bucket histogram -> global bucket totals ----

__global__ __launch_bounds__(256) void chunk_hist(const int* __restrict__ dst,
                                                  int* __restrict__ btot) {
    __shared__ int h[NBK];
    int t = threadIdx.x;
    for (int k = t; k < NBK; k += 256) h[k] = 0;
    __syncthreads();
    int e0 = blockIdx.x * CHUNK;
    for (int i = t; i < CHUNK; i += 256) atomicAdd(&h[dst[e0 + i] >> 9], 1);
    __syncthreads();
    for (int k = t; k < NBK; k += 256)
        if (h[k]) atomicAdd(&btot[k], h[k]);
}

// ---------------- pass 2: scan bucket totals -> bases & cursors ----------------

__global__ void bucket_scan(const int* __restrict__ btot, int* __restrict__ bbase,
                            int* __restrict__ bcur, int* __restrict__ offs) {
    __shared__ int s[256];
    int t = threadIdx.x;
    int v = (t < NBK) ? btot[t] : 0;
    s[t] = v; __syncthreads();
    for (int d = 1; d < 256; d <<= 1) {
        int x = (t >= d) ? s[t - d] : 0;
        __syncthreads();
        s[t] += x;
        __syncthreads();
    }
    if (t < NBK) { int b = s[t] - v; bbase[t] = b; bcur[t] = b; }
    if (t == 0) offs[N_NODES] = N_EDGES;
}

// ---------------- pass 3: LDS-staged scatter into bucket-grouped pairs ---------
// Each block bins its chunk in LDS, reserves ONE contiguous run per bucket
// (single atomic), then flushes runs sequentially -> full-line writes from one
// CU; no cross-XCD partial-line thrash (R5's bucket_scatter lesson).

__global__ __launch_bounds__(256) void edge_scatter(const int* __restrict__ src,
                                                    const int* __restrict__ dst,
                                                    int* __restrict__ bcur,
                                                    int2* __restrict__ pairs) {
    __shared__ int2 buf[CHUNK];                 // 50 KB
    __shared__ int lcnt[NBK], lloc[NBK], lcur[NBK];
    int t = threadIdx.x;
    for (int k = t; k < NBK; k += 256) { lcnt[k] = 0; lcur[k] = 0; }
    __syncthreads();
    int e0 = blockIdx.x * CHUNK;
    for (int i = t; i < CHUNK; i += 256) atomicAdd(&lcnt[dst[e0 + i] >> 9], 1);
    __syncthreads();
    // exclusive scan of lcnt (NBK <= 256) via 256-wide Hillis-Steele
    {
        __shared__ int s[256];
        int v = (t < NBK) ? lcnt[t] : 0;
        s[t] = v; __syncthreads();
        for (int d = 1; d < 256; d <<= 1) {
            int x = (t >= d) ? s[t - d] : 0;
            __syncthreads();
            s[t] += x;
            __syncthreads();
        }
        if (t < NBK) lloc[t] = s[t] - v;
    }
    __syncthreads();
    for (int i = t; i < CHUNK; i += 256) {
        int d = dst[e0 + i];
        int k = d >> 9;
        int li = lloc[k] + atomicAdd(&lcur[k], 1);
        buf[li] = make_int2(src[e0 + i], d);
    }
    __syncthreads();
    for (int k = t; k < NBK; k += 256) {
        int c = lcnt[k];
        if (c) {
            int g = atomicAdd(&bcur[k], c);
            int lo = lloc[k];
            for (int j = 0; j < c; j++) pairs[g + j] = buf[lo + j];
        }
    }
}

// ---------------- pass 4: per-bucket exact CSR + degree/dinv/offs --------------
// One block per 512-node bucket; everything local -> no global atomics, no
// global scan, sequential reads and writes.

__global__ __launch_bounds__(512) void bucket_place(const int2* __restrict__ pairs,
                                                    const int* __restrict__ bbase,
                                                    const int* __restrict__ btot,
                                                    int* __restrict__ offs,
                                                    float* __restrict__ dinv,
                                                    int* __restrict__ csr) {
    __shared__ int lcnt[512];
    __shared__ int lofs[512];
    __shared__ int lcur[512];
    __shared__ int lsrc[PLACE_CAP];             // 32 KB
    int t = threadIdx.x;
    int b = blockIdx.x;
    int node0 = b << 9;
    int nn = min(512, N_NODES - node0);
    int beg = bbase[b], cnt = btot[b];
    lcnt[t] = 0; lcur[t] = 0;
    __syncthreads();
    for (int i = t; i < cnt; i += 512)
        atomicAdd(&lcnt[pairs[beg + i].y - node0], 1);
    __syncthreads();
    int deg = lcnt[t];
    for (int d = 1; d < 512; d <<= 1) {          // inclusive scan in place
        int x = (t >= d) ? lcnt[t - d] : 0;
        __syncthreads();
        lcnt[t] += x;
        __syncthreads();
    }
    lofs[t] = lcnt[t] - deg;
    if (t < nn) {
        offs[node0 + t] = beg + lcnt[t] - deg;
        dinv[node0 + t] = 1.0f / sqrtf((float)deg + 1.0f);
    }
    __syncthreads();
    for (int i = t; i < cnt; i += 512) {
        int2 pr = pairs[beg + i];
        int n = pr.y - node0;
        int li = lofs[n] + atomicAdd(&lcur[n], 1);
        if (li < PLACE_CAP) lsrc[li] = pr.x;
        else                csr[beg + li] = pr.x;   // paranoia fallback
    }
    __syncthreads();
    int lim = min(cnt, PLACE_CAP);
    for (int j = t; j < lim; j += 512) csr[beg + j] = lsrc[j];
}

// ---------------- fp32 GEMM [N x 64] @ [64 x 64], fp16 output ----------------
// R1-proven structure: acc[4][4] (16 VGPRs), no spills. DO NOT grow the
// accumulator tile: R2's acc[8][4] variant hit VGPR=256 -> scratch spills.

__global__ __launch_bounds__(256) void gemm64(const float* __restrict__ X,
                                              const float* __restrict__ W,
                                              __half* __restrict__ H) {
    __shared__ float Xt[64][68];   // transposed tile: Xt[k][node]
    __shared__ float Ws[64][64];   // Ws[k][j]
    int t = threadIdx.x;
    int base = blockIdx.x * 64;

    {
        const float4* Wv = (const float4*)W;
        float4* Wsv = (float4*)Ws;
        Wsv[t]        = Wv[t];
        Wsv[t + 256]  = Wv[t + 256];
        Wsv[t + 512]  = Wv[t + 512];
        Wsv[t + 768]  = Wv[t + 768];
    }
    {
        int r = t >> 2;
        int k0 = (t & 3) * 16;
        int row = base + r;
        if (row < N_NODES) {
            const float4* xr = (const float4*)(X + (size_t)row * 64 + k0);
            #pragma unroll
            for (int q = 0; q < 4; q++) {
                float4 v = xr[q];
                int k = k0 + q * 4;
                Xt[k + 0][r] = v.x; Xt[k + 1][r] = v.y;
                Xt[k + 2][r] = v.z; Xt[k + 3][r] = v.w;
            }
        } else {
            #pragma unroll
            for (int q = 0; q < 4; q++) {
                int k = k0 + q * 4;
                Xt[k][r] = 0.f; Xt[k + 1][r] = 0.f; Xt[k + 2][r] = 0.f; Xt[k + 3][r] = 0.f;
            }
        }
    }
    __syncthreads();

    int tx = t & 15, ty = t >> 4;
    int j0 = tx * 4, n0 = ty * 4;
    float acc[4][4] = {};
    #pragma unroll
    for (int k = 0; k < 64; k++) {
        float4 a = *(const float4*)&Xt[k][n0];
        float4 w = *(const float4*)&Ws[k][j0];
        acc[0][0] += a.x * w.x; acc[0][1] += a.x * w.y; acc[0][2] += a.x * w.z; acc[0][3] += a.x * w.w;
        acc[1][0] += a.y * w.x; acc[1][1] += a.y * w.y; acc[1][2] += a.y * w.z; acc[1][3] += a.y * w.w;
        acc[2][0] += a.z * w.x; acc[2][1] += a.z * w.y; acc[2][2] += a.z * w.z; acc[2][3] += a.z * w.w;
        acc[3][0] += a.w * w.x; acc[3][1] += a.w * w.y; acc[3][2] += a.w * w.z; acc[3][3] += a.w * w.w;
    }
    #pragma unroll
    for (int i = 0; i < 4; i++) {
        int row = base + n0 + i;
        if (row < N_NODES) {
            __half2 h01 = __float22half2_rn(make_float2(acc[i][0], acc[i][1]));
            __half2 h23 = __float22half2_rn(make_float2(acc[i][2], acc[i][3]));
            uint2 u;
            u.x = *(unsigned int*)&h01;
            u.y = *(unsigned int*)&h23;
            *(uint2*)((char*)H + (size_t)row * 128 + j0 * 2) = u;
        }
    }
}

// ------------- aggregation: wave per node, 4 edge-subgroups x 16 feature-quads -------------
// H fp16 (row = 128B = 16 uint2); csr holds src only, norm = dinv[src]*dinv[dst]
// computed on the fly (dinv is 400KB, L2-resident).

__device__ inline void agg_body(const uint2* __restrict__ Hh, int wid, int lane,
                                const int* __restrict__ offs,
                                const int* __restrict__ csr,
                                const float* __restrict__ dinv,
                                float4& out) {
    int eg = lane >> 4;       // 0..3
    int fq = lane & 15;       // feature quad
    int beg = offs[wid], end = offs[wid + 1];
    float di = dinv[wid];
    uint2 us = Hh[(size_t)wid * 16 + fq];

    float4 a0 = {0.f, 0.f, 0.f, 0.f};
    float4 a1 = {0.f, 0.f, 0.f, 0.f};
    int e = beg + eg;
    for (; e + 4 < end; e += 8) {
        int s0 = csr[e];
        int s1 = csr[e + 4];
        float n0 = dinv[s0] * di, n1 = dinv[s1] * di;
        uint2 u0 = Hh[(size_t)s0 * 16 + fq];
        uint2 u1 = Hh[(size_t)s1 * 16 + fq];
        float2 f00 = __half22float2(*(__half2*)&u0.x);
        float2 f01 = __half22float2(*(__half2*)&u0.y);
        float2 f10 = __half22float2(*(__half2*)&u1.x);
        float2 f11 = __half22float2(*(__half2*)&u1.y);
        a0.x += f00.x * n0; a0.y += f00.y * n0; a0.z += f01.x * n0; a0.w += f01.y * n0;
        a1.x += f10.x * n1; a1.y += f10.y * n1; a1.z += f11.x * n1; a1.w += f11.y * n1;
    }
    if (e < end) {
        int s0 = csr[e];
        float n0 = dinv[s0] * di;
        uint2 u0 = Hh[(size_t)s0 * 16 + fq];
        float2 f00 = __half22float2(*(__half2*)&u0.x);
        float2 f01 = __half22float2(*(__half2*)&u0.y);
        a0.x += f00.x * n0; a0.y += f00.y * n0; a0.z += f01.x * n0; a0.w += f01.y * n0;
    }
    a0.x += a1.x; a0.y += a1.y; a0.z += a1.z; a0.w += a1.w;
    a0.x += __shfl_xor(a0.x, 16); a0.y += __shfl_xor(a0.y, 16);
    a0.z += __shfl_xor(a0.z, 16); a0.w += __shfl_xor(a0.w, 16);
    a0.x += __shfl_xor(a0.x, 32); a0.y += __shfl_xor(a0.y, 32);
    a0.z += __shfl_xor(a0.z, 32); a0.w += __shfl_xor(a0.w, 32);
    float2 s01 = __half22float2(*(__half2*)&us.x);
    float2 s23 = __half22float2(*(__half2*)&us.y);
    float dd = di * di;
    out.x = a0.x + s01.x * dd; out.y = a0.y + s01.y * dd;
    out.z = a0.z + s23.x * dd; out.w = a0.w + s23.y * dd;
}

__global__ __launch_bounds__(256) void agg_gcn(const __half* __restrict__ H,
                                               const int* __restrict__ offs,
                                               const int* __restrict__ csr,
                                               const float* __restrict__ dinv,
                                               const float* __restrict__ bias,
                                               float* __restrict__ Out) {
    int wid = (blockIdx.x * 256 + threadIdx.x) >> 6;
    int lane = threadIdx.x & 63;
    if (wid >= N_NODES) return;
    float4 r;
    agg_body((const uint2*)H, wid, lane, offs, csr, dinv, r);
    int fq = lane & 15;
    if ((lane >> 4) == 0) {
        float4 b4 = ((const float4*)bias)[fq];
        float4 o;
        o.x = fmaxf(r.x + b4.x, 0.f); o.y = fmaxf(r.y + b4.y, 0.f);
        o.z = fmaxf(r.z + b4.z, 0.f); o.w = fmaxf(r.w + b4.w, 0.f);
        ((float4*)Out)[(size_t)wid * 16 + fq] = o;
    }
}

__global__ __launch_bounds__(256) void agg_gcn_pool(const __half* __restrict__ H,
                                                    const int* __restrict__ offs,
                                                    const int* __restrict__ csr,
                                                    const float* __restrict__ dinv,
                                                    const float* __restrict__ bias,
                                                    const float* __restrict__ fcw,
                                                    float* __restrict__ p) {
    int wid = (blockIdx.x * 256 + threadIdx.x) >> 6;
    int lane = threadIdx.x & 63;
    if (wid >= N_NODES) return;
    float4 r;
    agg_body((const uint2*)H, wid, lane, offs, csr, dinv, r);
    int fq = lane & 15;
    float4 b4 = ((const float4*)bias)[fq];
    float4 f4 = ((const float4*)fcw)[fq];
    float v = fmaxf(r.x + b4.x, 0.f) * f4.x + fmaxf(r.y + b4.y, 0.f) * f4.y
            + fmaxf(r.z + b4.z, 0.f) * f4.z + fmaxf(r.w + b4.w, 0.f) * f4.w;
    v += __shfl_xor(v, 1); v += __shfl_xor(v, 2);
    v += __shfl_xor(v, 4); v += __shfl_xor(v, 8);
    if (lane == 0) p[wid] = v;
}

// ---------------- per-graph segmented mean via binary search (no atomics) ----

__device__ inline int lower_bound_batch(const int* __restrict__ batch, int key) {
    int lo = 0, hi = N_NODES;
    while (lo < hi) {
        int mid = (lo + hi) >> 1;
        if (batch[mid] < key) lo = mid + 1; else hi = mid;
    }
    return lo;
}

__global__ __launch_bounds__(256) void graph_reduce(const float* __restrict__ p,
                                                    const int* __restrict__ batch,
                                                    const float* __restrict__ fcb,
                                                    float* __restrict__ out) {
    __shared__ float red[4];
    int g = blockIdx.x;
    int s0 = lower_bound_batch(batch, g);
    int s1 = lower_bound_batch(batch, g + 1);
    float acc = 0.f;
    for (int i = s0 + threadIdx.x; i < s1; i += 256) acc += p[i];
    #pragma unroll
    for (int o = 32; o > 0; o >>= 1) acc += __shfl_xor(acc, o);
    int lane = threadIdx.x & 63, wv = threadIdx.x >> 6;
    if (lane == 0) red[wv] = acc;
    __syncthreads();
    if (threadIdx.x == 0) {
        float sum = red[0] + red[1] + red[2] + red[3];
        out[g] = sum / fmaxf((float)(s1 - s0), 1.f) + fcb[0];
    }
}

// ---------------- launch ----------------

extern "C" void kernel_launch(void* const* d_in, const int* in_sizes, int n_in,
                              void* d_out, int out_size, void* d_ws, size_t ws_size,
                              hipStream_t stream) {
    const float* x    = (const float*)d_in[0];
    const int*   ei   = (const int*)d_in[1];
    const int*   batch= (const int*)d_in[2];
    const float* w0   = (const float*)d_in[3];
    const float* b0   = (const float*)d_in[4];
    const float* w1   = (const float*)d_in[5];
    const float* b1   = (const float*)d_in[6];
    const float* w2   = (const float*)d_in[7];
    const float* b2   = (const float*)d_in[8];
    const float* fcw  = (const float*)d_in[9];
    const float* fcb  = (const float*)d_in[10];
    float* out = (float*)d_out;

    const int* src_e = ei;              // edge_index[0]
    const int* dst_e = ei + N_EDGES;    // edge_index[1]

    char* w = (char*)d_ws;
    size_t o = 0;
    int*    btot  = (int*)(w + o);    o += 256 * 4;
    int*    bbase = (int*)(w + o);    o += 256 * 4;
    int*    bcur  = (int*)(w + o);    o += 256 * 4;
    int*    offs  = (int*)(w + o);    o += (size_t)(N_NODES + 8) * 4;   // N+1 used
    float*  dinv  = (float*)(w + o);  o += (size_t)N_NODES * 4;
    int2*   pairs = (int2*)(w + o);   o += (size_t)N_EDGES * 8;         // 10.24MB
    int*    csr   = (int*)(w + o);    o += (size_t)N_EDGES * 4;         // 5.12MB
    __half* bufA  = (__half*)(w + o); o += (size_t)N_NODES * 64 * 2;    // 12.8MB
    float*  bufB  = (float*)(w + o);  o += (size_t)N_NODES * 64 * 4;    // 25.6MB
    float*  pvec  = (float*)(w + o);  o += (size_t)N_NODES * 4;

    hipMemsetAsync(btot, 0, 256 * 4, stream);

    chunk_hist<<<NCH, 256, 0, stream>>>(dst_e, btot);
    bucket_scan<<<1, 256, 0, stream>>>(btot, bbase, bcur, offs);
    edge_scatter<<<NCH, 256, 0, stream>>>(src_e, dst_e, bcur, pairs);
    bucket_place<<<NBK, 512, 0, stream>>>(pairs, bbase, btot, offs, dinv, csr);

    const int GEMM_BLOCKS = (N_NODES + 63) / 64;   // 1563
    const int AGG_BLOCKS  = (N_NODES + 3) / 4;     // 25000

    gemm64<<<GEMM_BLOCKS, 256, 0, stream>>>(x, w0, bufA);
    agg_gcn<<<AGG_BLOCKS, 256, 0, stream>>>(bufA, offs, csr, dinv, b0, bufB);

    gemm64<<<GEMM_BLOCKS, 256, 0, stream>>>(bufB, w1, bufA);
    agg_gcn<<<AGG_BLOCKS, 256, 0, stream>>>(bufA, offs, csr, dinv, b1, bufB);

    gemm64<<<GEMM_BLOCKS, 256, 0, stream>>>(bufB, w2, bufA);
    agg_gcn_pool<<<AGG_BLOCKS, 256, 0, stream>>>(bufA, offs, csr, dinv, b2, fcw, pvec);

    graph_reduce<<<N_GRAPHS, 256, 0, stream>>>(pvec, batch, fcb, out);
}

// Round 8
// 392.507 us; speedup vs baseline: 1.2875x; 1.0370x over previous
//
#include <hip/hip_runtime.h>
#include <hip/hip_fp16.h>
#include <type_traits>

#define N_NODES 100000
#define N_EDGES 1280000
#define N_GRAPHS 512
#define NBK 196          // buckets of 512 dst nodes: ceil(100000/512)
#define CHUNK 6400       // edges per scatter block; 200*6400 == N_EDGES exactly
#define NCH 200
#define PLACE_CAP 8192   // bucket mean 6554, sigma ~80 -> 20 sigma headroom

// ---------------- pass 1: per-chunk bucket histogram -> global bucket totals ----

__global__ __launch_bounds__(256) void chunk_hist(const int* __restrict__ dst,
                                                  int* __restrict__ btot) {
    __shared__ int h[NBK];
    int t = threadIdx.x;
    for (int k = t; k < NBK; k += 256) h[k] = 0;
    __syncthreads();
    int e0 = blockIdx.x * CHUNK;
    for (int i = t; i < CHUNK; i += 256) atomicAdd(&h[dst[e0 + i] >> 9], 1);
    __syncthreads();
    for (int k = t; k < NBK; k += 256)
        if (h[k]) atomicAdd(&btot[k], h[k]);
}

// ---------------- pass 2: scan bucket totals -> bases & cursors ----------------

__global__ void bucket_scan(const int* __restrict__ btot, int* __restrict__ bbase,
                            int* __restrict__ bcur, int* __restrict__ offs) {
    __shared__ int s[256];
    int t = threadIdx.x;
    int v = (t < NBK) ? btot[t] : 0;
    s[t] = v; __syncthreads();
    for (int d = 1; d < 256; d <<= 1) {
        int x = (t >= d) ? s[t - d] : 0;
        __syncthreads();
        s[t] += x;
        __syncthreads();
    }
    if (t < NBK) { int b = s[t] - v; bbase[t] = b; bcur[t] = b; }
    if (t == 0) offs[N_NODES] = N_EDGES;
}

// ---------------- pass 3: LDS-staged scatter into bucket-grouped pairs ---------
// Each block bins its chunk in LDS, reserves ONE contiguous run per bucket
// (single atomic), then flushes runs sequentially -> full-line writes from one
// CU; no cross-XCD partial-line thrash (R5's bucket_scatter lesson).

__global__ __launch_bounds__(256) void edge_scatter(const int* __restrict__ src,
                                                    const int* __restrict__ dst,
                                                    int* __restrict__ bcur,
                                                    int2* __restrict__ pairs) {
    __shared__ int2 buf[CHUNK];                 // 50 KB
    __shared__ int lcnt[NBK], lloc[NBK], lcur[NBK];
    int t = threadIdx.x;
    for (int k = t; k < NBK; k += 256) { lcnt[k] = 0; lcur[k] = 0; }
    __syncthreads();
    int e0 = blockIdx.x * CHUNK;
    for (int i = t; i < CHUNK; i += 256) atomicAdd(&lcnt[dst[e0 + i] >> 9], 1);
    __syncthreads();
    {
        __shared__ int s[256];
        int v = (t < NBK) ? lcnt[t] : 0;
        s[t] = v; __syncthreads();
        for (int d = 1; d < 256; d <<= 1) {
            int x = (t >= d) ? s[t - d] : 0;
            __syncthreads();
            s[t] += x;
            __syncthreads();
        }
        if (t < NBK) lloc[t] = s[t] - v;
    }
    __syncthreads();
    for (int i = t; i < CHUNK; i += 256) {
        int d = dst[e0 + i];
        int k = d >> 9;
        int li = lloc[k] + atomicAdd(&lcur[k], 1);
        buf[li] = make_int2(src[e0 + i], d);
    }
    __syncthreads();
    for (int k = t; k < NBK; k += 256) {
        int c = lcnt[k];
        if (c) {
            int g = atomicAdd(&bcur[k], c);
            int lo = lloc[k];
            for (int j = 0; j < c; j++) pairs[g + j] = buf[lo + j];
        }
    }
}

// ---------------- pass 4: per-bucket exact CSR + degree/dinv/offs --------------

__global__ __launch_bounds__(512) void bucket_place(const int2* __restrict__ pairs,
                                                    const int* __restrict__ bbase,
                                                    const int* __restrict__ btot,
                                                    int* __restrict__ offs,
                                                    float* __restrict__ dinv,
                                                    int* __restrict__ csr) {
    __shared__ int lcnt[512];
    __shared__ int lofs[512];
    __shared__ int lcur[512];
    __shared__ int lsrc[PLACE_CAP];             // 32 KB
    int t = threadIdx.x;
    int b = blockIdx.x;
    int node0 = b << 9;
    int nn = min(512, N_NODES - node0);
    int beg = bbase[b], cnt = btot[b];
    lcnt[t] = 0; lcur[t] = 0;
    __syncthreads();
    for (int i = t; i < cnt; i += 512)
        atomicAdd(&lcnt[pairs[beg + i].y - node0], 1);
    __syncthreads();
    int deg = lcnt[t];
    for (int d = 1; d < 512; d <<= 1) {
        int x = (t >= d) ? lcnt[t - d] : 0;
        __syncthreads();
        lcnt[t] += x;
        __syncthreads();
    }
    lofs[t] = lcnt[t] - deg;
    if (t < nn) {
        offs[node0 + t] = beg + lcnt[t] - deg;
        dinv[node0 + t] = 1.0f / sqrtf((float)deg + 1.0f);
    }
    __syncthreads();
    for (int i = t; i < cnt; i += 512) {
        int2 pr = pairs[beg + i];
        int n = pr.y - node0;
        int li = lofs[n] + atomicAdd(&lcur[n], 1);
        if (li < PLACE_CAP) lsrc[li] = pr.x;
        else                csr[beg + li] = pr.x;
    }
    __syncthreads();
    int lim = min(cnt, PLACE_CAP);
    for (int j = t; j < lim; j += 512) csr[beg + j] = lsrc[j];
}

// ---------------- GEMM [N x 64] @ [64 x 64], templated input, fp16 output -----
// R1-proven structure: acc[4][4] (16 VGPRs), no spills. DO NOT grow the
// accumulator tile: R2's acc[8][4] variant hit VGPR=256 -> scratch spills.

template <typename T>
__global__ __launch_bounds__(256) void gemm64(const T* __restrict__ X,
                                              const float* __restrict__ W,
                                              __half* __restrict__ H) {
    __shared__ float Xt[64][68];   // transposed tile: Xt[k][node]
    __shared__ float Ws[64][64];   // Ws[k][j]
    int t = threadIdx.x;
    int base = blockIdx.x * 64;

    {
        const float4* Wv = (const float4*)W;
        float4* Wsv = (float4*)Ws;
        Wsv[t]        = Wv[t];
        Wsv[t + 256]  = Wv[t + 256];
        Wsv[t + 512]  = Wv[t + 512];
        Wsv[t + 768]  = Wv[t + 768];
    }
    {
        int r = t >> 2;
        int k0 = (t & 3) * 16;
        int row = base + r;
        if (row < N_NODES) {
            if constexpr (std::is_same<T, float>::value) {
                const float4* xr = (const float4*)(X + (size_t)row * 64 + k0);
                #pragma unroll
                for (int q = 0; q < 4; q++) {
                    float4 v = xr[q];
                    int k = k0 + q * 4;
                    Xt[k + 0][r] = v.x; Xt[k + 1][r] = v.y;
                    Xt[k + 2][r] = v.z; Xt[k + 3][r] = v.w;
                }
            } else {
                const uint2* xr = (const uint2*)((const __half*)X + (size_t)row * 64 + k0);
                #pragma unroll
                for (int q = 0; q < 4; q++) {
                    uint2 u = xr[q];
                    float2 fa = __half22float2(*(__half2*)&u.x);
                    float2 fb = __half22float2(*(__half2*)&u.y);
                    int k = k0 + q * 4;
                    Xt[k + 0][r] = fa.x; Xt[k + 1][r] = fa.y;
                    Xt[k + 2][r] = fb.x; Xt[k + 3][r] = fb.y;
                }
            }
        } else {
            #pragma unroll
            for (int q = 0; q < 16; q++) Xt[k0 + q][r] = 0.f;
        }
    }
    __syncthreads();

    int tx = t & 15, ty = t >> 4;
    int j0 = tx * 4, n0 = ty * 4;
    float acc[4][4] = {};
    #pragma unroll
    for (int k = 0; k < 64; k++) {
        float4 a = *(const float4*)&Xt[k][n0];
        float4 w = *(const float4*)&Ws[k][j0];
        acc[0][0] += a.x * w.x; acc[0][1] += a.x * w.y; acc[0][2] += a.x * w.z; acc[0][3] += a.x * w.w;
        acc[1][0] += a.y * w.x; acc[1][1] += a.y * w.y; acc[1][2] += a.y * w.z; acc[1][3] += a.y * w.w;
        acc[2][0] += a.z * w.x; acc[2][1] += a.z * w.y; acc[2][2] += a.z * w.z; acc[2][3] += a.z * w.w;
        acc[3][0] += a.w * w.x; acc[3][1] += a.w * w.y; acc[3][2] += a.w * w.z; acc[3][3] += a.w * w.w;
    }
    #pragma unroll
    for (int i = 0; i < 4; i++) {
        int row = base + n0 + i;
        if (row < N_NODES) {
            __half2 h01 = __float22half2_rn(make_float2(acc[i][0], acc[i][1]));
            __half2 h23 = __float22half2_rn(make_float2(acc[i][2], acc[i][3]));
            uint2 u;
            u.x = *(unsigned int*)&h01;
            u.y = *(unsigned int*)&h23;
            *(uint2*)((char*)H + (size_t)row * 128 + j0 * 2) = u;
        }
    }
}

// ------------- aggregation: wave per node, 4 edge-subgroups x 16 feature-quads -------------
// Flat predicated 4-deep gather: 16 edges/chunk, all 4 csr loads + 4 H-gathers
// + 4 dinv loads in flight before any waitcnt-dependent use. csr is padded by
// 16 ints; OOB slots select src=0 (row 0 stays hot) with norm forced to 0.

__device__ inline void agg_body(const uint2* __restrict__ Hh, int wid, int lane,
                                const int* __restrict__ offs,
                                const int* __restrict__ csr,
                                const float* __restrict__ dinv,
                                float4& out) {
    int eg = lane >> 4;       // 0..3
    int fq = lane & 15;       // feature quad
    int beg = offs[wid], end = offs[wid + 1];
    float di = dinv[wid];
    uint2 us = Hh[(size_t)wid * 16 + fq];

    float4 a0 = {0.f, 0.f, 0.f, 0.f};
    float4 a1 = {0.f, 0.f, 0.f, 0.f};
    for (int base = beg; base < end; base += 16) {
        int i0 = base + eg;
        int r0 = csr[i0], r1 = csr[i0 + 4], r2 = csr[i0 + 8], r3 = csr[i0 + 12];
        bool p0 = i0      < end, p1 = i0 + 4  < end,
             p2 = i0 + 8  < end, p3 = i0 + 12 < end;
        int s0 = p0 ? r0 : 0, s1 = p1 ? r1 : 0,
            s2 = p2 ? r2 : 0, s3 = p3 ? r3 : 0;
        uint2 u0 = Hh[(size_t)s0 * 16 + fq];
        uint2 u1 = Hh[(size_t)s1 * 16 + fq];
        uint2 u2 = Hh[(size_t)s2 * 16 + fq];
        uint2 u3 = Hh[(size_t)s3 * 16 + fq];
        float d0 = dinv[s0], d1 = dinv[s1], d2 = dinv[s2], d3 = dinv[s3];
        float n0 = p0 ? d0 * di : 0.f;
        float n1 = p1 ? d1 * di : 0.f;
        float n2 = p2 ? d2 * di : 0.f;
        float n3 = p3 ? d3 * di : 0.f;
        float2 f00 = __half22float2(*(__half2*)&u0.x);
        float2 f01 = __half22float2(*(__half2*)&u0.y);
        float2 f10 = __half22float2(*(__half2*)&u1.x);
        float2 f11 = __half22float2(*(__half2*)&u1.y);
        float2 f20 = __half22float2(*(__half2*)&u2.x);
        float2 f21 = __half22float2(*(__half2*)&u2.y);
        float2 f30 = __half22float2(*(__half2*)&u3.x);
        float2 f31 = __half22float2(*(__half2*)&u3.y);
        a0.x += f00.x * n0; a0.y += f00.y * n0; a0.z += f01.x * n0; a0.w += f01.y * n0;
        a1.x += f10.x * n1; a1.y += f10.y * n1; a1.z += f11.x * n1; a1.w += f11.y * n1;
        a0.x += f20.x * n2; a0.y += f20.y * n2; a0.z += f21.x * n2; a0.w += f21.y * n2;
        a1.x += f30.x * n3; a1.y += f30.y * n3; a1.z += f31.x * n3; a1.w += f31.y * n3;
    }
    a0.x += a1.x; a0.y += a1.y; a0.z += a1.z; a0.w += a1.w;
    a0.x += __shfl_xor(a0.x, 16); a0.y += __shfl_xor(a0.y, 16);
    a0.z += __shfl_xor(a0.z, 16); a0.w += __shfl_xor(a0.w, 16);
    a0.x += __shfl_xor(a0.x, 32); a0.y += __shfl_xor(a0.y, 32);
    a0.z += __shfl_xor(a0.z, 32); a0.w += __shfl_xor(a0.w, 32);
    float2 s01 = __half22float2(*(__half2*)&us.x);
    float2 s23 = __half22float2(*(__half2*)&us.y);
    float dd = di * di;
    out.x = a0.x + s01.x * dd; out.y = a0.y + s01.y * dd;
    out.z = a0.z + s23.x * dd; out.w = a0.w + s23.y * dd;
}

__global__ __launch_bounds__(256) void agg_gcn(const __half* __restrict__ H,
                                               const int* __restrict__ offs,
                                               const int* __restrict__ csr,
                                               const float* __restrict__ dinv,
                                               const float* __restrict__ bias,
                                               __half* __restrict__ Out) {
    int wid = (blockIdx.x * 256 + threadIdx.x) >> 6;
    int lane = threadIdx.x & 63;
    if (wid >= N_NODES) return;
    float4 r;
    agg_body((const uint2*)H, wid, lane, offs, csr, dinv, r);
    int fq = lane & 15;
    if ((lane >> 4) == 0) {
        float4 b4 = ((const float4*)bias)[fq];
        __half2 h01 = __float22half2_rn(make_float2(fmaxf(r.x + b4.x, 0.f),
                                                    fmaxf(r.y + b4.y, 0.f)));
        __half2 h23 = __float22half2_rn(make_float2(fmaxf(r.z + b4.z, 0.f),
                                                    fmaxf(r.w + b4.w, 0.f)));
        uint2 u;
        u.x = *(unsigned int*)&h01;
        u.y = *(unsigned int*)&h23;
        ((uint2*)Out)[(size_t)wid * 16 + fq] = u;
    }
}

__global__ __launch_bounds__(256) void agg_gcn_pool(const __half* __restrict__ H,
                                                    const int* __restrict__ offs,
                                                    const int* __restrict__ csr,
                                                    const float* __restrict__ dinv,
                                                    const float* __restrict__ bias,
                                                    const float* __restrict__ fcw,
                                                    float* __restrict__ p) {
    int wid = (blockIdx.x * 256 + threadIdx.x) >> 6;
    int lane = threadIdx.x & 63;
    if (wid >= N_NODES) return;
    float4 r;
    agg_body((const uint2*)H, wid, lane, offs, csr, dinv, r);
    int fq = lane & 15;
    float4 b4 = ((const float4*)bias)[fq];
    float4 f4 = ((const float4*)fcw)[fq];
    float v = fmaxf(r.x + b4.x, 0.f) * f4.x + fmaxf(r.y + b4.y, 0.f) * f4.y
            + fmaxf(r.z + b4.z, 0.f) * f4.z + fmaxf(r.w + b4.w, 0.f) * f4.w;
    v += __shfl_xor(v, 1); v += __shfl_xor(v, 2);
    v += __shfl_xor(v, 4); v += __shfl_xor(v, 8);
    if (lane == 0) p[wid] = v;
}

// ---------------- per-graph segmented mean via binary search (no atomics) ----

__device__ inline int lower_bound_batch(const int* __restrict__ batch, int key) {
    int lo = 0, hi = N_NODES;
    while (lo < hi) {
        int mid = (lo + hi) >> 1;
        if (batch[mid] < key) lo = mid + 1; else hi = mid;
    }
    return lo;
}

__global__ __launch_bounds__(256) void graph_reduce(const float* __restrict__ p,
                                                    const int* __restrict__ batch,
                                                    const float* __restrict__ fcb,
                                                    float* __restrict__ out) {
    __shared__ float red[4];
    int g = blockIdx.x;
    int s0 = lower_bound_batch(batch, g);
    int s1 = lower_bound_batch(batch, g + 1);
    float acc = 0.f;
    for (int i = s0 + threadIdx.x; i < s1; i += 256) acc += p[i];
    #pragma unroll
    for (int o = 32; o > 0; o >>= 1) acc += __shfl_xor(acc, o);
    int lane = threadIdx.x & 63, wv = threadIdx.x >> 6;
    if (lane == 0) red[wv] = acc;
    __syncthreads();
    if (threadIdx.x == 0) {
        float sum = red[0] + red[1] + red[2] + red[3];
        out[g] = sum / fmaxf((float)(s1 - s0), 1.f) + fcb[0];
    }
}

// ---------------- launch ----------------

extern "C" void kernel_launch(void* const* d_in, const int* in_sizes, int n_in,
                              void* d_out, int out_size, void* d_ws, size_t ws_size,
                              hipStream_t stream) {
    const float* x    = (const float*)d_in[0];
    const int*   ei   = (const int*)d_in[1];
    const int*   batch= (const int*)d_in[2];
    const float* w0   = (const float*)d_in[3];
    const float* b0   = (const float*)d_in[4];
    const float* w1   = (const float*)d_in[5];
    const float* b1   = (const float*)d_in[6];
    const float* w2   = (const float*)d_in[7];
    const float* b2   = (const float*)d_in[8];
    const float* fcw  = (const float*)d_in[9];
    const float* fcb  = (const float*)d_in[10];
    float* out = (float*)d_out;

    const int* src_e = ei;              // edge_index[0]
    const int* dst_e = ei + N_EDGES;    // edge_index[1]

    char* w = (char*)d_ws;
    size_t o = 0;
    int*    btot  = (int*)(w + o);    o += 256 * 4;
    int*    bbase = (int*)(w + o);    o += 256 * 4;
    int*    bcur  = (int*)(w + o);    o += 256 * 4;
    int*    offs  = (int*)(w + o);    o += (size_t)(N_NODES + 8) * 4;   // N+1 used
    float*  dinv  = (float*)(w + o);  o += (size_t)N_NODES * 4;
    int2*   pairs = (int2*)(w + o);   o += (size_t)N_EDGES * 8;         // 10.24MB
    int*    csr   = (int*)(w + o);    o += (size_t)(N_EDGES + 16) * 4;  // +16 pad for 4-deep agg
    __half* bufA  = (__half*)(w + o); o += (size_t)N_NODES * 64 * 2;    // 12.8MB
    __half* bufB  = (__half*)(w + o); o += (size_t)N_NODES * 64 * 2;    // 12.8MB
    float*  pvec  = (float*)(w + o);  o += (size_t)N_NODES * 4;

    hipMemsetAsync(btot, 0, 256 * 4, stream);
    hipMemsetAsync(csr + N_EDGES, 0, 16 * 4, stream);   // sane pad (avoid 0xAA poison)

    chunk_hist<<<NCH, 256, 0, stream>>>(dst_e, btot);
    bucket_scan<<<1, 256, 0, stream>>>(btot, bbase, bcur, offs);
    edge_scatter<<<NCH, 256, 0, stream>>>(src_e, dst_e, bcur, pairs);
    bucket_place<<<NBK, 512, 0, stream>>>(pairs, bbase, btot, offs, dinv, csr);

    const int GEMM_BLOCKS = (N_NODES + 63) / 64;   // 1563
    const int AGG_BLOCKS  = (N_NODES + 3) / 4;     // 25000

    gemm64<float><<<GEMM_BLOCKS, 256, 0, stream>>>(x, w0, bufA);
    agg_gcn<<<AGG_BLOCKS, 256, 0, stream>>>(bufA, offs, csr, dinv, b0, bufB);

    gemm64<__half><<<GEMM_BLOCKS, 256, 0, stream>>>(bufB, w1, bufA);
    agg_gcn<<<AGG_BLOCKS, 256, 0, stream>>>(bufA, offs, csr, dinv, b1, bufB);

    gemm64<__half><<<GEMM_BLOCKS, 256, 0, stream>>>(bufB, w2, bufA);
    agg_gcn_pool<<<AGG_BLOCKS, 256, 0, stream>>>(bufA, offs, csr, dinv, b2, fcw, pvec);

    graph_reduce<<<N_GRAPHS, 256, 0, stream>>>(pvec, batch, fcb, out);
}

// Round 9
// 305.324 us; speedup vs baseline: 1.6551x; 1.2855x over previous
//
#include <hip/hip_runtime.h>
#include <hip/hip_fp16.h>

#define N_NODES 100000
#define N_EDGES 1280000
#define N_GRAPHS 512
#define NBK 196          // buckets of 512 dst nodes: ceil(100000/512)
#define CHUNK 6400       // edges per scatter block; 200*6400 == N_EDGES exactly
#define NCH 200
#define PLACE_CAP 8192   // bucket mean 6554, sigma ~80 -> 20 sigma headroom

typedef _Float16 v8h __attribute__((ext_vector_type(8)));
typedef float v4f __attribute__((ext_vector_type(4)));

// ---------------- pass 1: per-chunk bucket histogram -> global bucket totals ----

__global__ __launch_bounds__(256) void chunk_hist(const int* __restrict__ dst,
                                                  int* __restrict__ btot) {
    __shared__ int h[NBK];
    int t = threadIdx.x;
    for (int k = t; k < NBK; k += 256) h[k] = 0;
    __syncthreads();
    int e0 = blockIdx.x * CHUNK;
    for (int i = t; i < CHUNK; i += 256) atomicAdd(&h[dst[e0 + i] >> 9], 1);
    __syncthreads();
    for (int k = t; k < NBK; k += 256)
        if (h[k]) atomicAdd(&btot[k], h[k]);
}

// ---------------- pass 2: scan bucket totals -> bases & cursors ----------------

__global__ void bucket_scan(const int* __restrict__ btot, int* __restrict__ bbase,
                            int* __restrict__ bcur, int* __restrict__ offs) {
    __shared__ int s[256];
    int t = threadIdx.x;
    int v = (t < NBK) ? btot[t] : 0;
    s[t] = v; __syncthreads();
    for (int d = 1; d < 256; d <<= 1) {
        int x = (t >= d) ? s[t - d] : 0;
        __syncthreads();
        s[t] += x;
        __syncthreads();
    }
    if (t < NBK) { int b = s[t] - v; bbase[t] = b; bcur[t] = b; }
    if (t == 0) offs[N_NODES] = N_EDGES;
}

// ---------------- pass 3: LDS-staged scatter into bucket-grouped pairs ---------
// One contiguous run per bucket per block (single atomic) -> full-line writes
// from one CU; no cross-XCD partial-line thrash (R5 lesson).

__global__ __launch_bounds__(256) void edge_scatter(const int* __restrict__ src,
                                                    const int* __restrict__ dst,
                                                    int* __restrict__ bcur,
                                                    int2* __restrict__ pairs) {
    __shared__ int2 buf[CHUNK];                 // 50 KB
    __shared__ int lcnt[NBK], lloc[NBK], lcur[NBK];
    int t = threadIdx.x;
    for (int k = t; k < NBK; k += 256) { lcnt[k] = 0; lcur[k] = 0; }
    __syncthreads();
    int e0 = blockIdx.x * CHUNK;
    for (int i = t; i < CHUNK; i += 256) atomicAdd(&lcnt[dst[e0 + i] >> 9], 1);
    __syncthreads();
    {
        __shared__ int s[256];
        int v = (t < NBK) ? lcnt[t] : 0;
        s[t] = v; __syncthreads();
        for (int d = 1; d < 256; d <<= 1) {
            int x = (t >= d) ? s[t - d] : 0;
            __syncthreads();
            s[t] += x;
            __syncthreads();
        }
        if (t < NBK) lloc[t] = s[t] - v;
    }
    __syncthreads();
    for (int i = t; i < CHUNK; i += 256) {
        int d = dst[e0 + i];
        int k = d >> 9;
        int li = lloc[k] + atomicAdd(&lcur[k], 1);
        buf[li] = make_int2(src[e0 + i], d);
    }
    __syncthreads();
    for (int k = t; k < NBK; k += 256) {
        int c = lcnt[k];
        if (c) {
            int g = atomicAdd(&bcur[k], c);
            int lo = lloc[k];
            for (int j = 0; j < c; j++) pairs[g + j] = buf[lo + j];
        }
    }
}

// ---------------- pass 4: per-bucket exact CSR + degree/dinv/offs --------------

__global__ __launch_bounds__(512) void bucket_place(const int2* __restrict__ pairs,
                                                    const int* __restrict__ bbase,
                                                    const int* __restrict__ btot,
                                                    int* __restrict__ offs,
                                                    float* __restrict__ dinv,
                                                    int* __restrict__ csr) {
    __shared__ int lcnt[512];
    __shared__ int lofs[512];
    __shared__ int lcur[512];
    __shared__ int lsrc[PLACE_CAP];             // 32 KB
    int t = threadIdx.x;
    int b = blockIdx.x;
    int node0 = b << 9;
    int nn = min(512, N_NODES - node0);
    int beg = bbase[b], cnt = btot[b];
    lcnt[t] = 0; lcur[t] = 0;
    __syncthreads();
    for (int i = t; i < cnt; i += 512)
        atomicAdd(&lcnt[pairs[beg + i].y - node0], 1);
    __syncthreads();
    int deg = lcnt[t];
    for (int d = 1; d < 512; d <<= 1) {
        int x = (t >= d) ? lcnt[t - d] : 0;
        __syncthreads();
        lcnt[t] += x;
        __syncthreads();
    }
    lofs[t] = lcnt[t] - deg;
    if (t < nn) {
        offs[node0 + t] = beg + lcnt[t] - deg;
        dinv[node0 + t] = 1.0f / sqrtf((float)deg + 1.0f);
    }
    __syncthreads();
    for (int i = t; i < cnt; i += 512) {
        int2 pr = pairs[beg + i];
        int n = pr.y - node0;
        int li = lofs[n] + atomicAdd(&lcur[n], 1);
        if (li < PLACE_CAP) lsrc[li] = pr.x;
        else                csr[beg + li] = pr.x;
    }
    __syncthreads();
    int lim = min(cnt, PLACE_CAP);
    for (int j = t; j < lim; j += 512) csr[beg + j] = lsrc[j];
}

// ---------------- x -> fp16 cast (once) ----------------------------------------

__global__ __launch_bounds__(256) void xcast(const float* __restrict__ x,
                                             __half* __restrict__ xh) {
    int i = blockIdx.x * 256 + threadIdx.x;       // one float4 per thread
    if (i < (N_NODES * 64) / 4) {
        float4 v = ((const float4*)x)[i];
        __half2 h01 = __float22half2_rn(make_float2(v.x, v.y));
        __half2 h23 = __float22half2_rn(make_float2(v.z, v.w));
        uint2 u;
        u.x = *(unsigned int*)&h01;
        u.y = *(unsigned int*)&h23;
        ((uint2*)xh)[i] = u;
    }
}

// ---------------- MFMA fp16 GEMM [N x 64] @ [64 x 64] --------------------------
// Replaces the VALU gemm (R8 post-mortem: VGPR=252, 8.5% occupancy, 46us).
// Wave = 16 nodes x 64 cols: A-frag A[m=lane&15][k=quad*8+j] (m120-verified),
// B-frag B[k][n=lane&15] from W^T staged as half in LDS (stride 72 halves =
// 144B: 16B-aligned b128 reads, 2-way bank alias only), C/D col=lane&15,
// row=quad*4+reg (m89-verified). fp32 accumulate -> numerics unchanged.

__global__ __launch_bounds__(256) void gemm_mfma(const __half* __restrict__ X,
                                                 const float* __restrict__ W,
                                                 __half* __restrict__ H) {
    __shared__ _Float16 Wt[64][72];   // W^T in half: Wt[n][k]
    int t = threadIdx.x;
    {   // stage + transpose W (64x64 fp32, coalesced float4 reads)
        #pragma unroll
        for (int q = 0; q < 4; q++) {
            int idx = t + q * 256;        // float4 index into W
            int k = idx >> 4;
            int n0 = (idx & 15) * 4;
            float4 v = ((const float4*)W)[idx];
            Wt[n0 + 0][k] = (_Float16)v.x;
            Wt[n0 + 1][k] = (_Float16)v.y;
            Wt[n0 + 2][k] = (_Float16)v.z;
            Wt[n0 + 3][k] = (_Float16)v.w;
        }
    }
    __syncthreads();

    int wv = t >> 6, lane = t & 63;
    int m = lane & 15, quad = lane >> 4;

    v8h bf[4][2];                      // B-frags: (col-tile c, K-half h)
    #pragma unroll
    for (int c = 0; c < 4; c++)
        #pragma unroll
        for (int h = 0; h < 2; h++)
            bf[c][h] = *(const v8h*)&Wt[c * 16 + m][h * 32 + quad * 8];

    int base = blockIdx.x * 256 + wv * 64;
    #pragma unroll
    for (int tt = 0; tt < 4; tt++) {
        int tile = base + tt * 16;
        int rA = min(tile + m, N_NODES - 1);
        const _Float16* xp = (const _Float16*)X + (size_t)rA * 64 + quad * 8;
        v8h a0 = *(const v8h*)xp;
        v8h a1 = *(const v8h*)(xp + 32);
        v4f acc[4];
        #pragma unroll
        for (int c = 0; c < 4; c++) {
            acc[c] = (v4f){0.f, 0.f, 0.f, 0.f};
            acc[c] = __builtin_amdgcn_mfma_f32_16x16x32_f16(a0, bf[c][0], acc[c], 0, 0, 0);
            acc[c] = __builtin_amdgcn_mfma_f32_16x16x32_f16(a1, bf[c][1], acc[c], 0, 0, 0);
        }
        #pragma unroll
        for (int r = 0; r < 4; r++) {
            int row = tile + quad * 4 + r;
            if (row < N_NODES) {
                __half* hp = H + (size_t)row * 64 + m;
                #pragma unroll
                for (int c = 0; c < 4; c++)
                    hp[c * 16] = __float2half(acc[c][r]);
            }
        }
    }
}

// ------------- aggregation: wave per node, 4 edge-subgroups x 16 feature-quads -------------
// Flat predicated 4-deep gather; csr padded +16, OOB -> src 0 with norm 0.

__device__ inline void agg_body(const uint2* __restrict__ Hh, int wid, int lane,
                                const int* __restrict__ offs,
                                const int* __restrict__ csr,
                                const float* __restrict__ dinv,
                                float4& out) {
    int eg = lane >> 4;       // 0..3
    int fq = lane & 15;       // feature quad
    int beg = offs[wid], end = offs[wid + 1];
    float di = dinv[wid];
    uint2 us = Hh[(size_t)wid * 16 + fq];

    float4 a0 = {0.f, 0.f, 0.f, 0.f};
    float4 a1 = {0.f, 0.f, 0.f, 0.f};
    for (int base = beg; base < end; base += 16) {
        int i0 = base + eg;
        int r0 = csr[i0], r1 = csr[i0 + 4], r2 = csr[i0 + 8], r3 = csr[i0 + 12];
        bool p0 = i0      < end, p1 = i0 + 4  < end,
             p2 = i0 + 8  < end, p3 = i0 + 12 < end;
        int s0 = p0 ? r0 : 0, s1 = p1 ? r1 : 0,
            s2 = p2 ? r2 : 0, s3 = p3 ? r3 : 0;
        uint2 u0 = Hh[(size_t)s0 * 16 + fq];
        uint2 u1 = Hh[(size_t)s1 * 16 + fq];
        uint2 u2 = Hh[(size_t)s2 * 16 + fq];
        uint2 u3 = Hh[(size_t)s3 * 16 + fq];
        float d0 = dinv[s0], d1 = dinv[s1], d2 = dinv[s2], d3 = dinv[s3];
        float n0 = p0 ? d0 * di : 0.f;
        float n1 = p1 ? d1 * di : 0.f;
        float n2 = p2 ? d2 * di : 0.f;
        float n3 = p3 ? d3 * di : 0.f;
        float2 f00 = __half22float2(*(__half2*)&u0.x);
        float2 f01 = __half22float2(*(__half2*)&u0.y);
        float2 f10 = __half22float2(*(__half2*)&u1.x);
        float2 f11 = __half22float2(*(__half2*)&u1.y);
        float2 f20 = __half22float2(*(__half2*)&u2.x);
        float2 f21 = __half22float2(*(__half2*)&u2.y);
        float2 f30 = __half22float2(*(__half2*)&u3.x);
        float2 f31 = __half22float2(*(__half2*)&u3.y);
        a0.x += f00.x * n0; a0.y += f00.y * n0; a0.z += f01.x * n0; a0.w += f01.y * n0;
        a1.x += f10.x * n1; a1.y += f10.y * n1; a1.z += f11.x * n1; a1.w += f11.y * n1;
        a0.x += f20.x * n2; a0.y += f20.y * n2; a0.z += f21.x * n2; a0.w += f21.y * n2;
        a1.x += f30.x * n3; a1.y += f30.y * n3; a1.z += f31.x * n3; a1.w += f31.y * n3;
    }
    a0.x += a1.x; a0.y += a1.y; a0.z += a1.z; a0.w += a1.w;
    a0.x += __shfl_xor(a0.x, 16); a0.y += __shfl_xor(a0.y, 16);
    a0.z += __shfl_xor(a0.z, 16); a0.w += __shfl_xor(a0.w, 16);
    a0.x += __shfl_xor(a0.x, 32); a0.y += __shfl_xor(a0.y, 32);
    a0.z += __shfl_xor(a0.z, 32); a0.w += __shfl_xor(a0.w, 32);
    float2 s01 = __half22float2(*(__half2*)&us.x);
    float2 s23 = __half22float2(*(__half2*)&us.y);
    float dd = di * di;
    out.x = a0.x + s01.x * dd; out.y = a0.y + s01.y * dd;
    out.z = a0.z + s23.x * dd; out.w = a0.w + s23.y * dd;
}

__global__ __launch_bounds__(256) void agg_gcn(const __half* __restrict__ H,
                                               const int* __restrict__ offs,
                                               const int* __restrict__ csr,
                                               const float* __restrict__ dinv,
                                               const float* __restrict__ bias,
                                               __half* __restrict__ Out) {
    int wid = (blockIdx.x * 256 + threadIdx.x) >> 6;
    int lane = threadIdx.x & 63;
    if (wid >= N_NODES) return;
    float4 r;
    agg_body((const uint2*)H, wid, lane, offs, csr, dinv, r);
    int fq = lane & 15;
    if ((lane >> 4) == 0) {
        float4 b4 = ((const float4*)bias)[fq];
        __half2 h01 = __float22half2_rn(make_float2(fmaxf(r.x + b4.x, 0.f),
                                                    fmaxf(r.y + b4.y, 0.f)));
        __half2 h23 = __float22half2_rn(make_float2(fmaxf(r.z + b4.z, 0.f),
                                                    fmaxf(r.w + b4.w, 0.f)));
        uint2 u;
        u.x = *(unsigned int*)&h01;
        u.y = *(unsigned int*)&h23;
        ((uint2*)Out)[(size_t)wid * 16 + fq] = u;
    }
}

__global__ __launch_bounds__(256) void agg_gcn_pool(const __half* __restrict__ H,
                                                    const int* __restrict__ offs,
                                                    const int* __restrict__ csr,
                                                    const float* __restrict__ dinv,
                                                    const float* __restrict__ bias,
                                                    const float* __restrict__ fcw,
                                                    float* __restrict__ p) {
    int wid = (blockIdx.x * 256 + threadIdx.x) >> 6;
    int lane = threadIdx.x & 63;
    if (wid >= N_NODES) return;
    float4 r;
    agg_body((const uint2*)H, wid, lane, offs, csr, dinv, r);
    int fq = lane & 15;
    float4 b4 = ((const float4*)bias)[fq];
    float4 f4 = ((const float4*)fcw)[fq];
    float v = fmaxf(r.x + b4.x, 0.f) * f4.x + fmaxf(r.y + b4.y, 0.f) * f4.y
            + fmaxf(r.z + b4.z, 0.f) * f4.z + fmaxf(r.w + b4.w, 0.f) * f4.w;
    v += __shfl_xor(v, 1); v += __shfl_xor(v, 2);
    v += __shfl_xor(v, 4); v += __shfl_xor(v, 8);
    if (lane == 0) p[wid] = v;
}

// ---------------- per-graph segmented mean via binary search (no atomics) ----

__device__ inline int lower_bound_batch(const int* __restrict__ batch, int key) {
    int lo = 0, hi = N_NODES;
    while (lo < hi) {
        int mid = (lo + hi) >> 1;
        if (batch[mid] < key) lo = mid + 1; else hi = mid;
    }
    return lo;
}

__global__ __launch_bounds__(256) void graph_reduce(const float* __restrict__ p,
                                                    const int* __restrict__ batch,
                                                    const float* __restrict__ fcb,
                                                    float* __restrict__ out) {
    __shared__ float red[4];
    int g = blockIdx.x;
    int s0 = lower_bound_batch(batch, g);
    int s1 = lower_bound_batch(batch, g + 1);
    float acc = 0.f;
    for (int i = s0 + threadIdx.x; i < s1; i += 256) acc += p[i];
    #pragma unroll
    for (int o = 32; o > 0; o >>= 1) acc += __shfl_xor(acc, o);
    int lane = threadIdx.x & 63, wv = threadIdx.x >> 6;
    if (lane == 0) red[wv] = acc;
    __syncthreads();
    if (threadIdx.x == 0) {
        float sum = red[0] + red[1] + red[2] + red[3];
        out[g] = sum / fmaxf((float)(s1 - s0), 1.f) + fcb[0];
    }
}

// ---------------- launch ----------------

extern "C" void kernel_launch(void* const* d_in, const int* in_sizes, int n_in,
                              void* d_out, int out_size, void* d_ws, size_t ws_size,
                              hipStream_t stream) {
    const float* x    = (const float*)d_in[0];
    const int*   ei   = (const int*)d_in[1];
    const int*   batch= (const int*)d_in[2];
    const float* w0   = (const float*)d_in[3];
    const float* b0   = (const float*)d_in[4];
    const float* w1   = (const float*)d_in[5];
    const float* b1   = (const float*)d_in[6];
    const float* w2   = (const float*)d_in[7];
    const float* b2   = (const float*)d_in[8];
    const float* fcw  = (const float*)d_in[9];
    const float* fcb  = (const float*)d_in[10];
    float* out = (float*)d_out;

    const int* src_e = ei;              // edge_index[0]
    const int* dst_e = ei + N_EDGES;    // edge_index[1]

    char* w = (char*)d_ws;
    size_t o = 0;
    int*    btot  = (int*)(w + o);    o += 256 * 4;
    int*    bbase = (int*)(w + o);    o += 256 * 4;
    int*    bcur  = (int*)(w + o);    o += 256 * 4;
    int*    offs  = (int*)(w + o);    o += (size_t)(N_NODES + 8) * 4;   // N+1 used
    float*  dinv  = (float*)(w + o);  o += (size_t)N_NODES * 4;
    int2*   pairs = (int2*)(w + o);   o += (size_t)N_EDGES * 8;         // 10.24MB
    int*    csr   = (int*)(w + o);    o += (size_t)(N_EDGES + 16) * 4;  // +16 pad
    __half* xh    = (__half*)(w + o); o += (size_t)N_NODES * 64 * 2;    // 12.8MB
    __half* bufA  = (__half*)(w + o); o += (size_t)N_NODES * 64 * 2;    // 12.8MB
    __half* bufB  = (__half*)(w + o); o += (size_t)N_NODES * 64 * 2;    // 12.8MB
    float*  pvec  = (float*)(w + o);  o += (size_t)N_NODES * 4;

    hipMemsetAsync(btot, 0, 256 * 4, stream);
    hipMemsetAsync(csr + N_EDGES, 0, 16 * 4, stream);   // sane pad (avoid 0xAA poison)

    chunk_hist<<<NCH, 256, 0, stream>>>(dst_e, btot);
    bucket_scan<<<1, 256, 0, stream>>>(btot, bbase, bcur, offs);
    edge_scatter<<<NCH, 256, 0, stream>>>(src_e, dst_e, bcur, pairs);
    bucket_place<<<NBK, 512, 0, stream>>>(pairs, bbase, btot, offs, dinv, csr);
    xcast<<<(N_NODES * 64 / 4 + 255) / 256, 256, 0, stream>>>(x, xh);

    const int GEMM_BLOCKS = (N_NODES + 255) / 256;   // 391 (256 nodes/block)
    const int AGG_BLOCKS  = (N_NODES + 3) / 4;       // 25000

    gemm_mfma<<<GEMM_BLOCKS, 256, 0, stream>>>(xh, w0, bufA);
    agg_gcn<<<AGG_BLOCKS, 256, 0, stream>>>(bufA, offs, csr, dinv, b0, bufB);

    gemm_mfma<<<GEMM_BLOCKS, 256, 0, stream>>>(bufB, w1, bufA);
    agg_gcn<<<AGG_BLOCKS, 256, 0, stream>>>(bufA, offs, csr, dinv, b1, bufB);

    gemm_mfma<<<GEMM_BLOCKS, 256, 0, stream>>>(bufB, w2, bufA);
    agg_gcn_pool<<<AGG_BLOCKS, 256, 0, stream>>>(bufA, offs, csr, dinv, b2, fcw, pvec);

    graph_reduce<<<N_GRAPHS, 256, 0, stream>>>(pvec, batch, fcb, out);
}

// Round 10
// 295.714 us; speedup vs baseline: 1.7089x; 1.0325x over previous
//
#include <hip/hip_runtime.h>
#include <hip/hip_fp16.h>
#include <type_traits>

#define N_NODES 100000
#define N_EDGES 1280000
#define N_GRAPHS 512
#define NBK 196          // buckets of 512 dst nodes: ceil(100000/512)
#define CHUNK 3200       // edges per scatter block; 400*3200 == N_EDGES exactly
#define NCH 400
#define CAP 8192         // per-bucket region capacity: mean 6554, sigma ~81 -> 20 sigma

typedef _Float16 v8h __attribute__((ext_vector_type(8)));
typedef float v4f __attribute__((ext_vector_type(4)));

// fp16 x fp32 + fp32 fused (one VALU op; exact: fp16 operand widened in the FMA)
__device__ inline void fmix_lo(float& acc, unsigned h2, float n) {
    asm volatile("v_fma_mix_f32 %0, %1, %2, %0 op_sel:[0,0,0] op_sel_hi:[1,0,0]"
                 : "+v"(acc) : "v"(h2), "v"(n));
}
__device__ inline void fmix_hi(float& acc, unsigned h2, float n) {
    asm volatile("v_fma_mix_f32 %0, %1, %2, %0 op_sel:[1,0,0] op_sel_hi:[1,0,0]"
                 : "+v"(acc) : "v"(h2), "v"(n));
}

// ---------------- pass 1: LDS-staged scatter into fixed-capacity bucket regions ----
// Each block bins its chunk in LDS, reserves ONE contiguous run per bucket
// (single atomic on padded cursor), flushes runs sequentially -> full-line
// writes from one CU; no cross-XCD partial-line thrash (R5 lesson). Fixed
// regions (k*CAP) remove the need for a pre-pass histogram+scan.

__global__ __launch_bounds__(256) void edge_scatter(const int* __restrict__ src,
                                                    const int* __restrict__ dst,
                                                    int* __restrict__ bcur,
                                                    int2* __restrict__ pairs) {
    __shared__ int2 buf[CHUNK];                 // 25.6 KB
    __shared__ int lcnt[NBK], lloc[NBK], lcur[NBK];
    __shared__ int s[256];
    int t = threadIdx.x;
    for (int k = t; k < NBK; k += 256) { lcnt[k] = 0; lcur[k] = 0; }
    __syncthreads();
    int e0 = blockIdx.x * CHUNK;
    for (int i = t; i < CHUNK; i += 256) atomicAdd(&lcnt[dst[e0 + i] >> 9], 1);
    __syncthreads();
    {   // exclusive scan of lcnt (NBK <= 256)
        int v = (t < NBK) ? lcnt[t] : 0;
        s[t] = v; __syncthreads();
        for (int d = 1; d < 256; d <<= 1) {
            int x = (t >= d) ? s[t - d] : 0;
            __syncthreads();
            s[t] += x;
            __syncthreads();
        }
        if (t < NBK) lloc[t] = s[t] - v;
    }
    __syncthreads();
    for (int i = t; i < CHUNK; i += 256) {
        int d = dst[e0 + i];
        int k = d >> 9;
        int li = lloc[k] + atomicAdd(&lcur[k], 1);
        buf[li] = make_int2(src[e0 + i], d);
    }
    __syncthreads();
    for (int k = t; k < NBK; k += 256) {
        int c = lcnt[k];
        if (c) {
            int g = atomicAdd(&bcur[k * 16], c);
            int lo = lloc[k];
            int2* dstp = pairs + (size_t)k * CAP;
            for (int j = 0; j < c; j++)
                if (g + j < CAP) dstp[g + j] = buf[lo + j];   // clamp (20-sigma, never hit)
        }
    }
}

// ---------------- pass 2: scan bucket counts -> CSR bases ----------------------

__global__ void bucket_scan(const int* __restrict__ bcur, int* __restrict__ bbase,
                            int* __restrict__ offs) {
    __shared__ int s[256];
    int t = threadIdx.x;
    int v = (t < NBK) ? min(bcur[t * 16], CAP) : 0;
    s[t] = v; __syncthreads();
    for (int d = 1; d < 256; d <<= 1) {
        int x = (t >= d) ? s[t - d] : 0;
        __syncthreads();
        s[t] += x;
        __syncthreads();
    }
    if (t < NBK) bbase[t] = s[t] - v;
    if (t == 0) offs[N_NODES] = N_EDGES;
}

// ---------------- pass 3: per-bucket exact CSR + degree/dinv/offs --------------

__global__ __launch_bounds__(512) void bucket_place(const int2* __restrict__ pairs,
                                                    const int* __restrict__ bbase,
                                                    const int* __restrict__ bcur,
                                                    int* __restrict__ offs,
                                                    float* __restrict__ dinv,
                                                    int* __restrict__ csr) {
    __shared__ int lcnt[512];
    __shared__ int lofs[512];
    __shared__ int lcur[512];
    __shared__ int lsrc[CAP];                   // 32 KB
    int t = threadIdx.x;
    int b = blockIdx.x;
    int node0 = b << 9;
    int nn = min(512, N_NODES - node0);
    int beg = bbase[b];
    int cnt = min(bcur[b * 16], CAP);
    const int2* prs = pairs + (size_t)b * CAP;
    lcnt[t] = 0; lcur[t] = 0;
    __syncthreads();
    for (int i = t; i < cnt; i += 512)
        atomicAdd(&lcnt[prs[i].y - node0], 1);
    __syncthreads();
    int deg = lcnt[t];
    for (int d = 1; d < 512; d <<= 1) {
        int x = (t >= d) ? lcnt[t - d] : 0;
        __syncthreads();
        lcnt[t] += x;
        __syncthreads();
    }
    lofs[t] = lcnt[t] - deg;
    if (t < nn) {
        offs[node0 + t] = beg + lcnt[t] - deg;
        dinv[node0 + t] = 1.0f / sqrtf((float)deg + 1.0f);
    }
    __syncthreads();
    for (int i = t; i < cnt; i += 512) {
        int2 pr = prs[i];
        int n = pr.y - node0;
        int li = lofs[n] + atomicAdd(&lcur[n], 1);
        if (li < CAP) lsrc[li] = pr.x;
    }
    __syncthreads();
    for (int j = t; j < cnt; j += 512) csr[beg + j] = lsrc[j];
}

// ---------------- MFMA fp16 GEMM [N x 64] @ [64 x 64], templated input --------
// Wave = 16 nodes x 64 cols: A-frag A[m=lane&15][k=quad*8+j] (m120-verified),
// B-frag from W^T staged as half in LDS (stride 72 halves), C/D col=lane&15,
// row=quad*4+reg (m89-verified). fp32 accumulate. float path converts
// in-register (replaces the separate xcast kernel).

template <typename T>
__global__ __launch_bounds__(256) void gemm_mfma(const T* __restrict__ X,
                                                 const float* __restrict__ W,
                                                 __half* __restrict__ H) {
    __shared__ _Float16 Wt[64][72];   // W^T in half: Wt[n][k]
    int t = threadIdx.x;
    {   // stage + transpose W (64x64 fp32, coalesced float4 reads)
        #pragma unroll
        for (int q = 0; q < 4; q++) {
            int idx = t + q * 256;        // float4 index into W
            int k = idx >> 4;
            int n0 = (idx & 15) * 4;
            float4 v = ((const float4*)W)[idx];
            Wt[n0 + 0][k] = (_Float16)v.x;
            Wt[n0 + 1][k] = (_Float16)v.y;
            Wt[n0 + 2][k] = (_Float16)v.z;
            Wt[n0 + 3][k] = (_Float16)v.w;
        }
    }
    __syncthreads();

    int wv = t >> 6, lane = t & 63;
    int m = lane & 15, quad = lane >> 4;

    v8h bf[4][2];                      // B-frags: (col-tile c, K-half h)
    #pragma unroll
    for (int c = 0; c < 4; c++)
        #pragma unroll
        for (int h = 0; h < 2; h++)
            bf[c][h] = *(const v8h*)&Wt[c * 16 + m][h * 32 + quad * 8];

    int base = blockIdx.x * 256 + wv * 64;
    #pragma unroll
    for (int tt = 0; tt < 4; tt++) {
        int tile = base + tt * 16;
        int rA = min(tile + m, N_NODES - 1);
        v8h a0, a1;
        if constexpr (std::is_same<T, float>::value) {
            const float* xp = (const float*)X + (size_t)rA * 64 + quad * 8;
            float4 p0 = *(const float4*)xp;
            float4 p1 = *(const float4*)(xp + 4);
            float4 p2 = *(const float4*)(xp + 32);
            float4 p3 = *(const float4*)(xp + 36);
            a0 = (v8h){(_Float16)p0.x, (_Float16)p0.y, (_Float16)p0.z, (_Float16)p0.w,
                       (_Float16)p1.x, (_Float16)p1.y, (_Float16)p1.z, (_Float16)p1.w};
            a1 = (v8h){(_Float16)p2.x, (_Float16)p2.y, (_Float16)p2.z, (_Float16)p2.w,
                       (_Float16)p3.x, (_Float16)p3.y, (_Float16)p3.z, (_Float16)p3.w};
        } else {
            const _Float16* xp = (const _Float16*)X + (size_t)rA * 64 + quad * 8;
            a0 = *(const v8h*)xp;
            a1 = *(const v8h*)(xp + 32);
        }
        v4f acc[4];
        #pragma unroll
        for (int c = 0; c < 4; c++) {
            acc[c] = (v4f){0.f, 0.f, 0.f, 0.f};
            acc[c] = __builtin_amdgcn_mfma_f32_16x16x32_f16(a0, bf[c][0], acc[c], 0, 0, 0);
            acc[c] = __builtin_amdgcn_mfma_f32_16x16x32_f16(a1, bf[c][1], acc[c], 0, 0, 0);
        }
        #pragma unroll
        for (int r = 0; r < 4; r++) {
            int row = tile + quad * 4 + r;
            if (row < N_NODES) {
                __half* hp = H + (size_t)row * 64 + m;
                #pragma unroll
                for (int c = 0; c < 4; c++)
                    hp[c * 16] = __float2half(acc[c][r]);
            }
        }
    }
}

// ------------- aggregation: wave per node, 4 edge-subgroups x 16 feature-quads -------------
// Flat predicated 4-deep gather; csr padded +16, OOB -> src 0 with norm 0.
// Inner product via v_fma_mix_f32 (fp16 operand, fp32 accumulate): halves the
// per-edge VALU vs cvt+fma (R9: VALUBusy 53% was co-dominant with memory).

__device__ inline void agg_body(const uint2* __restrict__ Hh, int wid, int lane,
                                const int* __restrict__ offs,
                                const int* __restrict__ csr,
                                const float* __restrict__ dinv,
                                float4& out) {
    int eg = lane >> 4;       // 0..3
    int fq = lane & 15;       // feature quad
    int beg = offs[wid], end = offs[wid + 1];
    float di = dinv[wid];
    uint2 us = Hh[(size_t)wid * 16 + fq];

    float4 a0 = {0.f, 0.f, 0.f, 0.f};
    float4 a1 = {0.f, 0.f, 0.f, 0.f};
    for (int base = beg; base < end; base += 16) {
        int i0 = base + eg;
        int r0 = csr[i0], r1 = csr[i0 + 4], r2 = csr[i0 + 8], r3 = csr[i0 + 12];
        bool p0 = i0      < end, p1 = i0 + 4  < end,
             p2 = i0 + 8  < end, p3 = i0 + 12 < end;
        int s0 = p0 ? r0 : 0, s1 = p1 ? r1 : 0,
            s2 = p2 ? r2 : 0, s3 = p3 ? r3 : 0;
        uint2 u0 = Hh[(size_t)s0 * 16 + fq];
        uint2 u1 = Hh[(size_t)s1 * 16 + fq];
        uint2 u2 = Hh[(size_t)s2 * 16 + fq];
        uint2 u3 = Hh[(size_t)s3 * 16 + fq];
        float d0 = dinv[s0], d1 = dinv[s1], d2 = dinv[s2], d3 = dinv[s3];
        float n0 = p0 ? d0 * di : 0.f;
        float n1 = p1 ? d1 * di : 0.f;
        float n2 = p2 ? d2 * di : 0.f;
        float n3 = p3 ? d3 * di : 0.f;
        fmix_lo(a0.x, u0.x, n0); fmix_hi(a0.y, u0.x, n0);
        fmix_lo(a0.z, u0.y, n0); fmix_hi(a0.w, u0.y, n0);
        fmix_lo(a1.x, u1.x, n1); fmix_hi(a1.y, u1.x, n1);
        fmix_lo(a1.z, u1.y, n1); fmix_hi(a1.w, u1.y, n1);
        fmix_lo(a0.x, u2.x, n2); fmix_hi(a0.y, u2.x, n2);
        fmix_lo(a0.z, u2.y, n2); fmix_hi(a0.w, u2.y, n2);
        fmix_lo(a1.x, u3.x, n3); fmix_hi(a1.y, u3.x, n3);
        fmix_lo(a1.z, u3.y, n3); fmix_hi(a1.w, u3.y, n3);
    }
    a0.x += a1.x; a0.y += a1.y; a0.z += a1.z; a0.w += a1.w;
    a0.x += __shfl_xor(a0.x, 16); a0.y += __shfl_xor(a0.y, 16);
    a0.z += __shfl_xor(a0.z, 16); a0.w += __shfl_xor(a0.w, 16);
    a0.x += __shfl_xor(a0.x, 32); a0.y += __shfl_xor(a0.y, 32);
    a0.z += __shfl_xor(a0.z, 32); a0.w += __shfl_xor(a0.w, 32);
    float2 s01 = __half22float2(*(__half2*)&us.x);
    float2 s23 = __half22float2(*(__half2*)&us.y);
    float dd = di * di;
    out.x = a0.x + s01.x * dd; out.y = a0.y + s01.y * dd;
    out.z = a0.z + s23.x * dd; out.w = a0.w + s23.y * dd;
}

__global__ __launch_bounds__(256) void agg_gcn(const __half* __restrict__ H,
                                               const int* __restrict__ offs,
                                               const int* __restrict__ csr,
                                               const float* __restrict__ dinv,
                                               const float* __restrict__ bias,
                                               __half* __restrict__ Out) {
    int wid = (blockIdx.x * 256 + threadIdx.x) >> 6;
    int lane = threadIdx.x & 63;
    if (wid >= N_NODES) return;
    float4 r;
    agg_body((const uint2*)H, wid, lane, offs, csr, dinv, r);
    int fq = lane & 15;
    if ((lane >> 4) == 0) {
        float4 b4 = ((const float4*)bias)[fq];
        __half2 h01 = __float22half2_rn(make_float2(fmaxf(r.x + b4.x, 0.f),
                                                    fmaxf(r.y + b4.y, 0.f)));
        __half2 h23 = __float22half2_rn(make_float2(fmaxf(r.z + b4.z, 0.f),
                                                    fmaxf(r.w + b4.w, 0.f)));
        uint2 u;
        u.x = *(unsigned int*)&h01;
        u.y = *(unsigned int*)&h23;
        ((uint2*)Out)[(size_t)wid * 16 + fq] = u;
    }
}

__global__ __launch_bounds__(256) void agg_gcn_pool(const __half* __restrict__ H,
                                                    const int* __restrict__ offs,
                                                    const int* __restrict__ csr,
                                                    const float* __restrict__ dinv,
                                                    const float* __restrict__ bias,
                                                    const float* __restrict__ fcw,
                                                    float* __restrict__ p) {
    int wid = (blockIdx.x * 256 + threadIdx.x) >> 6;
    int lane = threadIdx.x & 63;
    if (wid >= N_NODES) return;
    float4 r;
    agg_body((const uint2*)H, wid, lane, offs, csr, dinv, r);
    int fq = lane & 15;
    float4 b4 = ((const float4*)bias)[fq];
    float4 f4 = ((const float4*)fcw)[fq];
    float v = fmaxf(r.x + b4.x, 0.f) * f4.x + fmaxf(r.y + b4.y, 0.f) * f4.y
            + fmaxf(r.z + b4.z, 0.f) * f4.z + fmaxf(r.w + b4.w, 0.f) * f4.w;
    v += __shfl_xor(v, 1); v += __shfl_xor(v, 2);
    v += __shfl_xor(v, 4); v += __shfl_xor(v, 8);
    if (lane == 0) p[wid] = v;
}

// ---------------- per-graph segmented mean via binary search (no atomics) ----

__device__ inline int lower_bound_batch(const int* __restrict__ batch, int key) {
    int lo = 0, hi = N_NODES;
    while (lo < hi) {
        int mid = (lo + hi) >> 1;
        if (batch[mid] < key) lo = mid + 1; else hi = mid;
    }
    return lo;
}

__global__ __launch_bounds__(256) void graph_reduce(const float* __restrict__ p,
                                                    const int* __restrict__ batch,
                                                    const float* __restrict__ fcb,
                                                    float* __restrict__ out) {
    __shared__ float red[4];
    int g = blockIdx.x;
    int s0 = lower_bound_batch(batch, g);
    int s1 = lower_bound_batch(batch, g + 1);
    float acc = 0.f;
    for (int i = s0 + threadIdx.x; i < s1; i += 256) acc += p[i];
    #pragma unroll
    for (int o = 32; o > 0; o >>= 1) acc += __shfl_xor(acc, o);
    int lane = threadIdx.x & 63, wv = threadIdx.x >> 6;
    if (lane == 0) red[wv] = acc;
    __syncthreads();
    if (threadIdx.x == 0) {
        float sum = red[0] + red[1] + red[2] + red[3];
        out[g] = sum / fmaxf((float)(s1 - s0), 1.f) + fcb[0];
    }
}

// ---------------- launch ----------------

extern "C" void kernel_launch(void* const* d_in, const int* in_sizes, int n_in,
                              void* d_out, int out_size, void* d_ws, size_t ws_size,
                              hipStream_t stream) {
    const float* x    = (const float*)d_in[0];
    const int*   ei   = (const int*)d_in[1];
    const int*   batch= (const int*)d_in[2];
    const float* w0   = (const float*)d_in[3];
    const float* b0   = (const float*)d_in[4];
    const float* w1   = (const float*)d_in[5];
    const float* b1   = (const float*)d_in[6];
    const float* w2   = (const float*)d_in[7];
    const float* b2   = (const float*)d_in[8];
    const float* fcw  = (const float*)d_in[9];
    const float* fcb  = (const float*)d_in[10];
    float* out = (float*)d_out;

    const int* src_e = ei;              // edge_index[0]
    const int* dst_e = ei + N_EDGES;    // edge_index[1]

    char* w = (char*)d_ws;
    size_t o = 0;
    int*    bcur  = (int*)(w + o);    o += 256 * 16 * 4;                // padded cursors
    int*    bbase = (int*)(w + o);    o += 256 * 4;
    int*    offs  = (int*)(w + o);    o += (size_t)(N_NODES + 8) * 4;   // N+1 used
    float*  dinv  = (float*)(w + o);  o += (size_t)N_NODES * 4;
    int2*   pairs = (int2*)(w + o);   o += (size_t)NBK * CAP * 8;       // 12.85MB
    int*    csr   = (int*)(w + o);    o += (size_t)(N_EDGES + 16) * 4;  // +16 pad
    __half* bufA  = (__half*)(w + o); o += (size_t)N_NODES * 64 * 2;    // 12.8MB
    __half* bufB  = (__half*)(w + o); o += (size_t)N_NODES * 64 * 2;    // 12.8MB
    float*  pvec  = (float*)(w + o);  o += (size_t)N_NODES * 4;

    hipMemsetAsync(bcur, 0, 256 * 16 * 4, stream);
    hipMemsetAsync(csr + N_EDGES, 0, 16 * 4, stream);   // sane pad (avoid 0xAA poison)

    edge_scatter<<<NCH, 256, 0, stream>>>(src_e, dst_e, bcur, pairs);
    bucket_scan<<<1, 256, 0, stream>>>(bcur, bbase, offs);
    bucket_place<<<NBK, 512, 0, stream>>>(pairs, bbase, bcur, offs, dinv, csr);

    const int GEMM_BLOCKS = (N_NODES + 255) / 256;   // 391 (256 nodes/block)
    const int AGG_BLOCKS  = (N_NODES + 3) / 4;       // 25000

    gemm_mfma<float><<<GEMM_BLOCKS, 256, 0, stream>>>(x, w0, bufA);
    agg_gcn<<<AGG_BLOCKS, 256, 0, stream>>>(bufA, offs, csr, dinv, b0, bufB);

    gemm_mfma<__half><<<GEMM_BLOCKS, 256, 0, stream>>>(bufB, w1, bufA);
    agg_gcn<<<AGG_BLOCKS, 256, 0, stream>>>(bufA, offs, csr, dinv, b1, bufB);

    gemm_mfma<__half><<<GEMM_BLOCKS, 256, 0, stream>>>(bufB, w2, bufA);
    agg_gcn_pool<<<AGG_BLOCKS, 256, 0, stream>>>(bufA, offs, csr, dinv, b2, fcw, pvec);

    graph_reduce<<<N_GRAPHS, 256, 0, stream>>>(pvec, batch, fcb, out);
}